// Round 14
// baseline (1699.764 us; speedup 1.0000x reference)
//
#include <hip/hip_runtime.h>
#include <hip/hip_bf16.h>

typedef __attribute__((ext_vector_type(8))) short short8;
typedef __attribute__((ext_vector_type(4))) float f32x4;

#define THREADS 512
#define MFMA(a, b, c) __builtin_amdgcn_mfma_f32_16x16x32_bf16((a), (b), (c), 0, 0, 0)
#define WAITV(N) asm volatile("s_waitcnt vmcnt(" #N ")" ::: "memory")
#define WAITLG0() asm volatile("s_waitcnt lgkmcnt(0)" ::: "memory")

static __device__ __forceinline__ unsigned short f2bf(float x) {
    __hip_bfloat16 h = __float2bfloat16(x);
    return __builtin_bit_cast(unsigned short, h);
}
static __device__ __forceinline__ unsigned pk2(float a, float b) {
    return (unsigned)f2bf(a) | ((unsigned)f2bf(b) << 16);
}
static __device__ __forceinline__ float bflo(unsigned u) {
    unsigned v = u << 16; return __builtin_bit_cast(float, v);
}
static __device__ __forceinline__ float bfhi(unsigned u) {
    unsigned v = u & 0xffff0000u; return __builtin_bit_cast(float, v);
}
static __device__ __forceinline__ float fast_tanh(float x) {
    float e = __builtin_amdgcn_exp2f(x * 2.885390081777927f);
    float r = __builtin_amdgcn_rcpf(e + 1.0f);
    return fmaf(-2.0f, r, 1.0f);
}
static __device__ __forceinline__ short8 cvt8(float4 a, float4 b) {
    short8 r;
    r[0] = (short)f2bf(a.x); r[1] = (short)f2bf(a.y);
    r[2] = (short)f2bf(a.z); r[3] = (short)f2bf(a.w);
    r[4] = (short)f2bf(b.x); r[5] = (short)f2bf(b.y);
    r[6] = (short)f2bf(b.z); r[7] = (short)f2bf(b.w);
    return r;
}
static __device__ __forceinline__ void gl_lds16f(const float* g, float* l) {
    __builtin_amdgcn_global_load_lds(
        (const __attribute__((address_space(1))) unsigned int*)g,
        (__attribute__((address_space(3))) unsigned int*)l, 16, 0, 0);   // aux=0: L2-cacheable
}

// Panel: 32 cols x 512 k bf16 in registers (AGPR-resident, R8/R12-proven).
// B-frag (verified): lane holds W[CB + nt*16 + (l&15)][kt*32 + (l>>4)*8 + e]
#define LOAD_PANEL(W, CB)                                                       \
    do {                                                                        \
        _Pragma("unroll")                                                       \
        for (int j = 0; j < 16; ++j) {                                          \
            const float* p0_ = (W) + (size_t)((CB) + c) * 512 + j * 32 + q * 8;       \
            const float* p1_ = (W) + (size_t)((CB) + 16 + c) * 512 + j * 32 + q * 8;  \
            float4 a0_ = *(const float4*)p0_, b0_ = *(const float4*)(p0_ + 4);  \
            float4 a1_ = *(const float4*)p1_, b1_ = *(const float4*)(p1_ + 4);  \
            bw0[j] = cvt8(a0_, b0_);                                            \
            bw1[j] = cvt8(a1_, b1_);                                            \
        }                                                                       \
    } while (0)

// Fused ring GEMM: nt 0,1 from AGPR panel; nt 2,3 streamed f32 from d_in via a
// per-wave-private 3-slot gl_lds ring (no barriers inside). Piece = one kt
// (2 nt x 512 f32 = 4KB/wave), 4 gl_lds instrs. Bijective unit swizzle:
// read-owner (l,h) <-> unit (2l+h)^((l>>4)&3). Invariant: 8 issues in flight at
// kt entry; stage kt+2 (4 issues) -> 12 -> WAITV(8) = kt's 4 resident. The
// invariant self-heals after any full drain (oldest-first retirement).
template<int PHASE, bool XPROJ>
static __device__ __forceinline__ void ring_gemm(
    const unsigned short* sfr, float* ringf,
    const float* __restrict__ Wh, const float* __restrict__ Wx,
    const short8 (&bw0)[16], const short8 (&bw1)[16],
    f32x4 (&acc)[2][4],
    const int w, const int l,
    const int s00, const int s01, const int s10, const int s11,
    const int u0off, const int u1off)
{
    #pragma unroll
    for (int kt = 0; kt < 16; ++kt) {
        const int slot  = (PHASE + kt) % 3;
        const int slotn = (PHASE + kt + 2) % 3;
        const int ktn   = (kt + 2) & 15;
        const float* gsrc = (XPROJ && kt < 14) ? Wx : Wh;
        WAITLG0();   // prior iter's ds_reads of slotn complete before DMA overwrite
        gl_lds16f(gsrc + s00 + ktn * 32, ringf + ((w * 3 + slotn) * 2 + 0) * 512);
        gl_lds16f(gsrc + s10 + ktn * 32, ringf + ((w * 3 + slotn) * 2 + 0) * 512 + 256);
        gl_lds16f(gsrc + s01 + ktn * 32, ringf + ((w * 3 + slotn) * 2 + 1) * 512);
        gl_lds16f(gsrc + s11 + ktn * 32, ringf + ((w * 3 + slotn) * 2 + 1) * 512 + 256);
        WAITV(8);
        short8 a0 = *(const short8*)(sfr + (kt * 64 + l) * 8);
        short8 a1 = *(const short8*)(sfr + ((16 + kt) * 64 + l) * 8);
        // panel halves (AGPR B operands)
        acc[0][0] = MFMA(a0, bw0[kt], acc[0][0]);
        acc[1][0] = MFMA(a1, bw0[kt], acc[1][0]);
        acc[0][1] = MFMA(a0, bw1[kt], acc[0][1]);
        acc[1][1] = MFMA(a1, bw1[kt], acc[1][1]);
        // streamed halves from ring
        {
            const float* pc = ringf + ((w * 3 + slot) * 2 + 0) * 512;
            float4 lo4 = *(const float4*)(pc + u0off);
            float4 hi4 = *(const float4*)(pc + u1off);
            short8 b = cvt8(lo4, hi4);
            acc[0][2] = MFMA(a0, b, acc[0][2]);
            acc[1][2] = MFMA(a1, b, acc[1][2]);
        }
        {
            const float* pc = ringf + ((w * 3 + slot) * 2 + 1) * 512;
            float4 lo4 = *(const float4*)(pc + u0off);
            float4 hi4 = *(const float4*)(pc + u1off);
            short8 b = cvt8(lo4, hi4);
            acc[0][3] = MFMA(a0, b, acc[0][3]);
            acc[1][3] = MFMA(a1, b, acc[1][3]);
        }
    }
}

// Direct-load f32-B GEMM (R9-verified) — head only.
template<int NT, int NKT_S>
static __device__ __forceinline__ void gemm_f32B(
    const unsigned short* sfr, const float* __restrict__ Wsrc,
    f32x4 (&acc)[2][NT], const int w, const int l)
{
    const int q = l >> 4, c = l & 15;
    const float* bp = Wsrc + (size_t)(w * (NT * 16) + c) * 512 + q * 8;
    float4 fa[NT][2], fb[NT][2];
    #pragma unroll
    for (int nt = 0; nt < NT; ++nt) {
        fa[nt][0] = *(const float4*)(bp + nt * 8192);
        fa[nt][1] = *(const float4*)(bp + nt * 8192 + 4);
    }
    #pragma unroll
    for (int kt = 0; kt < NKT_S; ++kt) {
        if (kt + 1 < NKT_S) {
            #pragma unroll
            for (int nt = 0; nt < NT; ++nt) {
                fb[nt][0] = *(const float4*)(bp + nt * 8192 + (kt + 1) * 32);
                fb[nt][1] = *(const float4*)(bp + nt * 8192 + (kt + 1) * 32 + 4);
            }
        }
        short8 a0 = *(const short8*)(sfr + (kt * 64 + l) * 8);
        short8 a1 = *(const short8*)(sfr + ((16 + kt) * 64 + l) * 8);
        #pragma unroll
        for (int nt = 0; nt < NT; ++nt) {
            short8 b = cvt8(fa[nt][0], fa[nt][1]);
            acc[0][nt] = MFMA(a0, b, acc[0][nt]);
            acc[1][nt] = MFMA(a1, b, acc[1][nt]);
        }
        if (kt + 1 < NKT_S) {
            #pragma unroll
            for (int nt = 0; nt < NT; ++nt) { fa[nt][0] = fb[nt][0]; fa[nt][1] = fb[nt][1]; }
        }
    }
}

static __device__ __forceinline__ void scatter_s(const float (&s)[2][4][4],
    unsigned short* sfrag, const int tIdx)
{
    #pragma unroll
    for (int mt = 0; mt < 2; ++mt)
        #pragma unroll
        for (int nt = 0; nt < 4; ++nt)
            #pragma unroll
            for (int i = 0; i < 4; ++i) {
                const int off = (mt * 16384 + (nt >> 1) * 1024 + ((2 * nt) & 3) * 256 + i * 16) >> 1;
                sfrag[tIdx + off] = f2bf(s[mt][nt][i]);
            }
}

// One step. History fully in registers (R1/R9/R10-verified):
// hh[0]=s_{t-2}, hh[1]=s_{t-3}, hh[2]=s_{t-4}; shift after use.
template<int PHASE>
static __device__ __forceinline__ void do_step(
    float (&s)[2][4][4], unsigned (&hh)[3][2][4][2], f32x4 (&acc)[2][4],
    const unsigned (&xpk)[2][4][2],
    unsigned short* sfrag, float* ringf,
    const float* __restrict__ Wh_w,
    const short8 (&bw0)[16], const short8 (&bw1)[16],
    const int w, const int l, const int tIdx,
    const int s00, const int s01, const int s10, const int s11,
    const int u0off, const int u1off,
    const float g1, const float g2, const float g3)
{
    scatter_s(s, sfrag, tIdx);
    WAITLG0(); __builtin_amdgcn_s_barrier();   // raw barrier: ring DMA stays in flight

    ring_gemm<PHASE, false>(sfrag, ringf, Wh_w, nullptr, bw0, bw1, acc,
                            w, l, s00, s01, s10, s11, u0off, u1off);
    WAITLG0(); __builtin_amdgcn_s_barrier();   // all sfrag reads done before next scatter

    #pragma unroll
    for (int mt = 0; mt < 2; ++mt)
        #pragma unroll
        for (int nt = 0; nt < 4; ++nt)
            #pragma unroll
            for (int p = 0; p < 2; ++p) {
                unsigned u1 = hh[0][mt][nt][p];
                unsigned u2 = hh[1][mt][nt][p];
                unsigned u3 = hh[2][mt][nt][p];
                unsigned ux = xpk[mt][nt][p];
                float pre0 = acc[mt][nt][2 * p] + bflo(ux)
                           + g1 * bflo(u1) + g2 * bflo(u2) + g3 * bflo(u3);
                float pre1 = acc[mt][nt][2 * p + 1] + bfhi(ux)
                           + g1 * bfhi(u1) + g2 * bfhi(u2) + g3 * bfhi(u3);
                float so0 = s[mt][nt][2 * p], so1 = s[mt][nt][2 * p + 1];
                s[mt][nt][2 * p]     = 0.5f * so0 + 0.5f * fast_tanh(pre0);
                s[mt][nt][2 * p + 1] = 0.5f * so1 + 0.5f * fast_tanh(pre1);
                hh[2][mt][nt][p] = u2;           // lag shift (verified)
                hh[1][mt][nt][p] = u1;
                hh[0][mt][nt][p] = pk2(so0, so1);
                acc[mt][nt][2 * p] = 0.f;
                acc[mt][nt][2 * p + 1] = 0.f;
            }
}

__global__ __attribute__((amdgpu_flat_work_group_size(512, 512), amdgpu_waves_per_eu(2, 2)))
void toroidal(
    const float* __restrict__ x,
    const float* __restrict__ Wx_w, const float* __restrict__ wxb,
    const float* __restrict__ Wh_w, const float* __restrict__ whb,
    const float* __restrict__ Hd_w, const float* __restrict__ hdb,
    const float* __restrict__ gamma_p, const float* __restrict__ alphas,
    const int* __restrict__ steps_p,
    float* __restrict__ out)
{
    __shared__ __align__(16) unsigned short sfrag[16384];   // 32 KB A-frags [mt2][kt16][lane64][e8]
    __shared__ __align__(16) float ringf[8 * 3 * 2 * 512];  // 96 KB ring [wave8][slot3][nt2][512 f32]

    const int tid = threadIdx.x;
    const int w = tid >> 6;
    const int l = tid & 63;
    const int q = l >> 4;
    const int c = l & 15;
    const int rbase = blockIdx.x * 32;

    const float gm = gamma_p[0];
    const float g1 = gm * alphas[0], g2 = gm * alphas[1], g3 = gm * alphas[2];
    const int nsteps = steps_p[0];

    float bsum[4];
    #pragma unroll
    for (int nt = 0; nt < 4; ++nt) {
        int col = w * 64 + nt * 16 + c;
        bsum[nt] = wxb[col] + whb[col];
    }
    const float hb0 = hdb[w * 32 + c], hb1 = hdb[w * 32 + 16 + c];

    // ---- staging source offsets (per lane; derived swizzle inverse) ----
    // unit = i*64 + l; sw=(unit>>5)&3; uu=unit^sw; owner lane lo=uu>>1, half h=uu&1
    const int cb2 = w * 64 + 32;
    int soff[2][2];
    #pragma unroll
    for (int i = 0; i < 2; ++i) {
        const int unit = i * 64 + l;
        const int sw = (unit >> 5) & 3;
        const int uu = unit ^ sw;
        const int lo = uu >> 1, hhalf = uu & 1;
        #pragma unroll
        for (int nt = 0; nt < 2; ++nt)
            soff[i][nt] = (cb2 + nt * 16 + (lo & 15)) * 512 + ((lo >> 4) & 3) * 8 + hhalf * 4;
    }
    const int s00 = soff[0][0], s01 = soff[0][1], s10 = soff[1][0], s11 = soff[1][1];
    // read offsets (f32 units): unit(h) = (2l+h)^((l>>4)&3)
    const int sw0 = (l >> 4) & 3;
    const int u0off = ((2 * l) ^ sw0) * 4;
    const int u1off = ((2 * l + 1) ^ sw0) * 4;

    // ---- pack x tile (32 rows) into sfrag as bf16 A-frags (verified) ----
    #pragma unroll
    for (int j = 0; j < 4; ++j) {
        int f = tid + j * THREADS;
        int mt = f >> 10;
        int kt = (f >> 6) & 15;
        int lf = f & 63;
        int row = mt * 16 + (lf & 15);
        int k0  = kt * 32 + (lf >> 4) * 8;
        const float* sp = x + (size_t)(rbase + row) * 512 + k0;
        float4 a = *(const float4*)sp;
        float4 b = *(const float4*)(sp + 4);
        short8 v = cvt8(a, b);
        *(short8*)&sfrag[(size_t)f * 8] = v;
    }

    short8 bw0[16], bw1[16];
    f32x4 acc[2][4];
    #pragma unroll
    for (int mt = 0; mt < 2; ++mt)
        #pragma unroll
        for (int nt = 0; nt < 4; ++nt)
            acc[mt][nt] = (f32x4){0.f, 0.f, 0.f, 0.f};

    LOAD_PANEL(Wx_w, w * 64);
    __syncthreads();    // sfrag visible + vmcnt drained -> clean ring baseline

    {   // prologue: stage Wx kt0 -> slot0, kt1 -> slot1 (8 issues in flight)
        #pragma unroll
        for (int k0s = 0; k0s < 2; ++k0s) {
            gl_lds16f(Wx_w + s00 + k0s * 32, ringf + ((w * 3 + k0s) * 2 + 0) * 512);
            gl_lds16f(Wx_w + s10 + k0s * 32, ringf + ((w * 3 + k0s) * 2 + 0) * 512 + 256);
            gl_lds16f(Wx_w + s01 + k0s * 32, ringf + ((w * 3 + k0s) * 2 + 1) * 512);
            gl_lds16f(Wx_w + s11 + k0s * 32, ringf + ((w * 3 + k0s) * 2 + 1) * 512 + 256);
        }
    }

    // ---- xproj (PHASE=0; tail kt=14,15 stages Wh kt0,kt1 into slots 1,2) ----
    ring_gemm<0, true>(sfrag, ringf, Wh_w, Wx_w, bw0, bw1, acc,
                       w, l, s00, s01, s10, s11, u0off, u1off);

    unsigned xpk[2][4][2];
    #pragma unroll
    for (int mt = 0; mt < 2; ++mt)
        #pragma unroll
        for (int nt = 0; nt < 4; ++nt) {
            float b = bsum[nt];
            xpk[mt][nt][0] = pk2(acc[mt][nt][0] + b, acc[mt][nt][1] + b);
            xpk[mt][nt][1] = pk2(acc[mt][nt][2] + b, acc[mt][nt][3] + b);
            acc[mt][nt] = (f32x4){0.f, 0.f, 0.f, 0.f};
        }
    WAITLG0(); __builtin_amdgcn_s_barrier();   // xproj sfrag reads done; DMA in flight

    // Wh panel (flat loads; their implicit waits drain the ring stages once —
    // the counted invariant self-heals in step 1, data already resident)
    LOAD_PANEL(Wh_w, w * 64);

    float s[2][4][4];
    unsigned hh[3][2][4][2];
    #pragma unroll
    for (int mt = 0; mt < 2; ++mt)
        #pragma unroll
        for (int nt = 0; nt < 4; ++nt) {
            #pragma unroll
            for (int i = 0; i < 4; ++i) s[mt][nt][i] = 0.f;
            #pragma unroll
            for (int a = 0; a < 3; ++a) { hh[a][mt][nt][0] = 0u; hh[a][mt][nt][1] = 0u; }
        }

    const int tIdx = (w * 2048 + q * 64 + (l & 7) * 2 + (((l >> 3) & 1) << 8)) >> 1;

    // ---- recurrence: PHASE cycles 1,2,0 (16 kt ≡ 1 mod 3) ----
    #define DS(P) do_step<P>(s, hh, acc, xpk, sfrag, ringf, Wh_w, bw0, bw1, \
                             w, l, tIdx, s00, s01, s10, s11, u0off, u1off, g1, g2, g3)
    int t = 0;
    while (t + 3 <= nsteps) {
        DS(1); DS(2); DS(0);
        t += 3;
    }
    if (t < nsteps) { DS(1); ++t; }
    if (t < nsteps) { DS(2); ++t; }
    #undef DS

    // ---- head: out = s_final @ Head^T + Head_b (R9-verified direct stream) ----
    scatter_s(s, sfrag, tIdx);
    WAITLG0(); __builtin_amdgcn_s_barrier();
    WAITV(0);   // drain leftover ring stages

    f32x4 acch[2][2];
    #pragma unroll
    for (int mt = 0; mt < 2; ++mt)
        #pragma unroll
        for (int nt = 0; nt < 2; ++nt)
            acch[mt][nt] = (f32x4){0.f, 0.f, 0.f, 0.f};
    gemm_f32B<2, 16>(sfrag, Hd_w, acch, w, l);

    #pragma unroll
    for (int nt = 0; nt < 2; ++nt) {
        int col = w * 32 + nt * 16 + c;
        float hb = nt ? hb1 : hb0;
        #pragma unroll
        for (int mt = 0; mt < 2; ++mt)
            #pragma unroll
            for (int i = 0; i < 4; ++i)
                out[(size_t)(rbase + mt * 16 + q * 4 + i) * 256 + col] = acch[mt][nt][i] + hb;
    }
}

extern "C" void kernel_launch(void* const* d_in, const int* in_sizes, int n_in,
                              void* d_out, int out_size, void* d_ws, size_t ws_size,
                              hipStream_t stream) {
    (void)n_in; (void)out_size; (void)d_ws; (void)ws_size;
    const float* x    = (const float*)d_in[0];
    const float* Wx_w = (const float*)d_in[1];
    const float* Wx_b = (const float*)d_in[2];
    const float* Wh_w = (const float*)d_in[3];
    const float* Wh_b = (const float*)d_in[4];
    const float* Hd_w = (const float*)d_in[5];
    const float* Hd_b = (const float*)d_in[6];
    const float* gma  = (const float*)d_in[7];
    const float* alp  = (const float*)d_in[8];
    const int*   stp  = (const int*)d_in[9];
    float* out = (float*)d_out;

    int batch = in_sizes[0] / 512;                 // 8192
    int nblk  = batch / 32;                        // 256 blocks, 1 per CU
    toroidal<<<nblk, THREADS, 0, stream>>>(x, Wx_w, Wx_b, Wh_w, Wh_b, Hd_w, Hd_b,
                                           gma, alp, stp, out);
}

// Round 15
// 1201.620 us; speedup vs baseline: 1.4146x; 1.4146x over previous
//
#include <hip/hip_runtime.h>
#include <hip/hip_bf16.h>

typedef __attribute__((ext_vector_type(8))) short short8;
typedef __attribute__((ext_vector_type(4))) float f32x4;

#define THREADS 512
#define MFMA(a, b, c) __builtin_amdgcn_mfma_f32_16x16x32_bf16((a), (b), (c), 0, 0, 0)
#define WAITV(N) asm volatile("s_waitcnt vmcnt(" #N ")" ::: "memory")
#define WAITLG0() asm volatile("s_waitcnt lgkmcnt(0)" ::: "memory")

static __device__ __forceinline__ unsigned short f2bf(float x) {
    __hip_bfloat16 h = __float2bfloat16(x);
    return __builtin_bit_cast(unsigned short, h);
}
static __device__ __forceinline__ unsigned pk2(float a, float b) {
    return (unsigned)f2bf(a) | ((unsigned)f2bf(b) << 16);
}
static __device__ __forceinline__ float bflo(unsigned u) {
    unsigned v = u << 16; return __builtin_bit_cast(float, v);
}
static __device__ __forceinline__ float bfhi(unsigned u) {
    unsigned v = u & 0xffff0000u; return __builtin_bit_cast(float, v);
}
static __device__ __forceinline__ float fast_tanh(float x) {
    float e = __builtin_amdgcn_exp2f(x * 2.885390081777927f);
    float r = __builtin_amdgcn_rcpf(e + 1.0f);
    return fmaf(-2.0f, r, 1.0f);
}
static __device__ __forceinline__ short8 cvt8(float4 a, float4 b) {
    short8 r;
    r[0] = (short)f2bf(a.x); r[1] = (short)f2bf(a.y);
    r[2] = (short)f2bf(a.z); r[3] = (short)f2bf(a.w);
    r[4] = (short)f2bf(b.x); r[5] = (short)f2bf(b.y);
    r[6] = (short)f2bf(b.z); r[7] = (short)f2bf(b.w);
    return r;
}
static __device__ __forceinline__ void gl_lds16f(const float* g, float* l) {
    __builtin_amdgcn_global_load_lds(
        (const __attribute__((address_space(1))) unsigned int*)g,
        (__attribute__((address_space(3))) unsigned int*)l, 16, 0, 0);   // aux=0: L2-cacheable
}

// Panel: 32 cols x 512 k bf16 in registers (AGPR side; R8/R12-proven).
// B-frag (verified): lane holds W[CB + nt*16 + (l&15)][kt*32 + (l>>4)*8 + e]
#define LOAD_PANEL(W, CB)                                                       \
    do {                                                                        \
        _Pragma("unroll")                                                       \
        for (int j = 0; j < 16; ++j) {                                          \
            const float* p0_ = (W) + (size_t)((CB) + c) * 512 + j * 32 + q * 8;       \
            const float* p1_ = (W) + (size_t)((CB) + 16 + c) * 512 + j * 32 + q * 8;  \
            float4 a0_ = *(const float4*)p0_, b0_ = *(const float4*)(p0_ + 4);  \
            float4 a1_ = *(const float4*)p1_, b1_ = *(const float4*)(p1_ + 4);  \
            bw0[j] = cvt8(a0_, b0_);                                            \
            bw1[j] = cvt8(a1_, b1_);                                            \
        }                                                                       \
    } while (0)

// Fused ring GEMM: nt 0,1 from AGPR panel; nt 2,3 streamed f32 from d_in via a
// per-wave-private 2-slot gl_lds ring (64 KB total; slot = kt&1). Piece = one kt
// (2 nt x 512 f32 = 4 KB/wave), 4 gl_lds instrs. Bijective unit swizzle
// (R14-verified correct): read-owner (l,h) <-> unit (2l+h)^((l>>4)&3).
// Invariant: 4 issues (chunk kt) in flight at kt entry; stage kt+1 (4 issues)
// -> 8 -> WAITV(4) = kt's 4 resident. Self-heals after any full drain.
// Staging at kt=15 targets the NEXT gemm's chunk 0 (slot 0): XPROJ stages Wh.
template<bool XPROJ>
static __device__ __forceinline__ void ring_gemm(
    const unsigned short* sfr, float* ringf,
    const float* __restrict__ Wh, const float* __restrict__ Wx,
    const short8 (&bw0)[16], const short8 (&bw1)[16],
    f32x4 (&acc)[2][4],
    const int w, const int l,
    const int s00, const int s01, const int s10, const int s11,
    const int u0off, const int u1off)
{
    #pragma unroll
    for (int kt = 0; kt < 16; ++kt) {
        const int slot  = kt & 1;
        const int slotn = (kt + 1) & 1;
        const int ktn   = (kt + 1) & 15;
        const float* gsrc = (XPROJ && kt < 15) ? Wx : Wh;
        WAITLG0();   // prior iter's ds_reads of slotn complete before DMA overwrite
        gl_lds16f(gsrc + s00 + ktn * 32, ringf + ((w * 2 + slotn) * 2 + 0) * 512);
        gl_lds16f(gsrc + s10 + ktn * 32, ringf + ((w * 2 + slotn) * 2 + 0) * 512 + 256);
        gl_lds16f(gsrc + s01 + ktn * 32, ringf + ((w * 2 + slotn) * 2 + 1) * 512);
        gl_lds16f(gsrc + s11 + ktn * 32, ringf + ((w * 2 + slotn) * 2 + 1) * 512 + 256);
        WAITV(4);
        short8 a0 = *(const short8*)(sfr + (kt * 64 + l) * 8);
        short8 a1 = *(const short8*)(sfr + ((16 + kt) * 64 + l) * 8);
        // panel halves (AGPR B operands)
        acc[0][0] = MFMA(a0, bw0[kt], acc[0][0]);
        acc[1][0] = MFMA(a1, bw0[kt], acc[1][0]);
        acc[0][1] = MFMA(a0, bw1[kt], acc[0][1]);
        acc[1][1] = MFMA(a1, bw1[kt], acc[1][1]);
        // streamed halves from ring
        {
            const float* pc = ringf + ((w * 2 + slot) * 2 + 0) * 512;
            float4 lo4 = *(const float4*)(pc + u0off);
            float4 hi4 = *(const float4*)(pc + u1off);
            short8 b = cvt8(lo4, hi4);
            acc[0][2] = MFMA(a0, b, acc[0][2]);
            acc[1][2] = MFMA(a1, b, acc[1][2]);
        }
        {
            const float* pc = ringf + ((w * 2 + slot) * 2 + 1) * 512;
            float4 lo4 = *(const float4*)(pc + u0off);
            float4 hi4 = *(const float4*)(pc + u1off);
            short8 b = cvt8(lo4, hi4);
            acc[0][3] = MFMA(a0, b, acc[0][3]);
            acc[1][3] = MFMA(a1, b, acc[1][3]);
        }
    }
}

// Direct-load f32-B GEMM (R9-verified) — head only.
template<int NT, int NKT_S>
static __device__ __forceinline__ void gemm_f32B(
    const unsigned short* sfr, const float* __restrict__ Wsrc,
    f32x4 (&acc)[2][NT], const int w, const int l)
{
    const int q = l >> 4, c = l & 15;
    const float* bp = Wsrc + (size_t)(w * (NT * 16) + c) * 512 + q * 8;
    float4 fa[NT][2], fb[NT][2];
    #pragma unroll
    for (int nt = 0; nt < NT; ++nt) {
        fa[nt][0] = *(const float4*)(bp + nt * 8192);
        fa[nt][1] = *(const float4*)(bp + nt * 8192 + 4);
    }
    #pragma unroll
    for (int kt = 0; kt < NKT_S; ++kt) {
        if (kt + 1 < NKT_S) {
            #pragma unroll
            for (int nt = 0; nt < NT; ++nt) {
                fb[nt][0] = *(const float4*)(bp + nt * 8192 + (kt + 1) * 32);
                fb[nt][1] = *(const float4*)(bp + nt * 8192 + (kt + 1) * 32 + 4);
            }
        }
        short8 a0 = *(const short8*)(sfr + (kt * 64 + l) * 8);
        short8 a1 = *(const short8*)(sfr + ((16 + kt) * 64 + l) * 8);
        #pragma unroll
        for (int nt = 0; nt < NT; ++nt) {
            short8 b = cvt8(fa[nt][0], fa[nt][1]);
            acc[0][nt] = MFMA(a0, b, acc[0][nt]);
            acc[1][nt] = MFMA(a1, b, acc[1][nt]);
        }
        if (kt + 1 < NKT_S) {
            #pragma unroll
            for (int nt = 0; nt < NT; ++nt) { fa[nt][0] = fb[nt][0]; fa[nt][1] = fb[nt][1]; }
        }
    }
}

static __device__ __forceinline__ void scatter_s(const float (&s)[2][4][4],
    unsigned short* sfrag, const int tIdx)
{
    #pragma unroll
    for (int mt = 0; mt < 2; ++mt)
        #pragma unroll
        for (int nt = 0; nt < 4; ++nt)
            #pragma unroll
            for (int i = 0; i < 4; ++i) {
                const int off = (mt * 16384 + (nt >> 1) * 1024 + ((2 * nt) & 3) * 256 + i * 16) >> 1;
                sfrag[tIdx + off] = f2bf(s[mt][nt][i]);
            }
}

// One step. SA = t&1 (R12-verified lag structure: h0 = s_{t-2} in regs,
// histu[SA] = s_{t-3}, histu[SA^1] = s_{t-4}, both tid-private in LDS).
template<int SA>
static __device__ __forceinline__ void do_step(
    float (&s)[2][4][4], unsigned (&h0)[2][4][2], f32x4 (&acc)[2][4],
    const unsigned (&xpk)[2][4][2],
    unsigned short* sfrag, unsigned* histu, float* ringf,
    const float* __restrict__ Wh_w,
    const short8 (&bw0)[16], const short8 (&bw1)[16],
    const int w, const int l, const int tid, const int tIdx,
    const int s00, const int s01, const int s10, const int s11,
    const int u0off, const int u1off,
    const float g1, const float g2, const float g3)
{
    scatter_s(s, sfrag, tIdx);
    WAITLG0(); __builtin_amdgcn_s_barrier();   // raw barrier: ring DMA stays in flight

    ring_gemm<false>(sfrag, ringf, Wh_w, nullptr, bw0, bw1, acc,
                     w, l, s00, s01, s10, s11, u0off, u1off);
    WAITLG0(); __builtin_amdgcn_s_barrier();   // all sfrag reads done before next scatter

    const int sB = SA ^ 1;
    #pragma unroll
    for (int mt = 0; mt < 2; ++mt)
        #pragma unroll
        for (int g = 0; g < 2; ++g) {
            uint4 hA = *(uint4*)&histu[((SA * 2 + mt) * 512 + tid) * 8 + g * 4];
            uint4 hB = *(uint4*)&histu[((sB * 2 + mt) * 512 + tid) * 8 + g * 4];
            uint4 nB;
            #pragma unroll
            for (int ntl = 0; ntl < 2; ++ntl) {
                const int nt = g * 2 + ntl;
                #pragma unroll
                for (int p = 0; p < 2; ++p) {
                    unsigned u1 = h0[mt][nt][p];
                    unsigned u2 = ((unsigned*)&hA)[ntl * 2 + p];
                    unsigned u3 = ((unsigned*)&hB)[ntl * 2 + p];
                    unsigned ux = xpk[mt][nt][p];
                    float pre0 = acc[mt][nt][2 * p] + bflo(ux)
                               + g1 * bflo(u1) + g2 * bflo(u2) + g3 * bflo(u3);
                    float pre1 = acc[mt][nt][2 * p + 1] + bfhi(ux)
                               + g1 * bfhi(u1) + g2 * bfhi(u2) + g3 * bfhi(u3);
                    float so0 = s[mt][nt][2 * p], so1 = s[mt][nt][2 * p + 1];
                    s[mt][nt][2 * p]     = 0.5f * so0 + 0.5f * fast_tanh(pre0);
                    s[mt][nt][2 * p + 1] = 0.5f * so1 + 0.5f * fast_tanh(pre1);
                    ((unsigned*)&nB)[ntl * 2 + p] = u1;     // s_{t-2} -> becomes s_{t'-4}
                    h0[mt][nt][p] = pk2(so0, so1);          // s_{t-1} for next step
                }
            }
            *(uint4*)&histu[((sB * 2 + mt) * 512 + tid) * 8 + g * 4] = nB;
            acc[mt][g * 2 + 0] = (f32x4){0.f, 0.f, 0.f, 0.f};
            acc[mt][g * 2 + 1] = (f32x4){0.f, 0.f, 0.f, 0.f};
        }
}

__global__ __attribute__((amdgpu_flat_work_group_size(512, 512), amdgpu_waves_per_eu(2, 2)))
void toroidal(
    const float* __restrict__ x,
    const float* __restrict__ Wx_w, const float* __restrict__ wxb,
    const float* __restrict__ Wh_w, const float* __restrict__ whb,
    const float* __restrict__ Hd_w, const float* __restrict__ hdb,
    const float* __restrict__ gamma_p, const float* __restrict__ alphas,
    const int* __restrict__ steps_p,
    float* __restrict__ out)
{
    __shared__ __align__(16) unsigned short sfrag[16384];     // 32 KB A-frags [mt2][kt16][lane64][e8]
    __shared__ __align__(16) float ringf[8 * 2 * 2 * 512];    // 64 KB ring [wave8][slot2][nt2][512 f32]
    __shared__ __align__(16) unsigned histu[2 * 2 * 512 * 8]; // 64 KB hist [slot2][mt2][tid][8 u32]

    const int tid = threadIdx.x;
    const int w = tid >> 6;
    const int l = tid & 63;
    const int q = l >> 4;
    const int c = l & 15;
    const int rbase = blockIdx.x * 32;

    const float gm = gamma_p[0];
    const float g1 = gm * alphas[0], g2 = gm * alphas[1], g3 = gm * alphas[2];
    const int nsteps = steps_p[0];

    float bsum[4];
    #pragma unroll
    for (int nt = 0; nt < 4; ++nt) {
        int col = w * 64 + nt * 16 + c;
        bsum[nt] = wxb[col] + whb[col];
    }
    const float hb0 = hdb[w * 32 + c], hb1 = hdb[w * 32 + 16 + c];

    // ---- staging source offsets (per lane; swizzle inverse — R14-verified) ----
    const int cb2 = w * 64 + 32;
    int soff[2][2];
    #pragma unroll
    for (int i = 0; i < 2; ++i) {
        const int unit = i * 64 + l;
        const int sw = (unit >> 5) & 3;
        const int uu = unit ^ sw;
        const int lo = uu >> 1, hhalf = uu & 1;
        #pragma unroll
        for (int nt = 0; nt < 2; ++nt)
            soff[i][nt] = (cb2 + nt * 16 + (lo & 15)) * 512 + ((lo >> 4) & 3) * 8 + hhalf * 4;
    }
    const int s00 = soff[0][0], s01 = soff[0][1], s10 = soff[1][0], s11 = soff[1][1];
    const int sw0 = (l >> 4) & 3;
    const int u0off = ((2 * l) ^ sw0) * 4;
    const int u1off = ((2 * l + 1) ^ sw0) * 4;

    // ---- pack x tile (32 rows) into sfrag as bf16 A-frags (verified) ----
    #pragma unroll
    for (int j = 0; j < 4; ++j) {
        int f = tid + j * THREADS;
        int mt = f >> 10;
        int kt = (f >> 6) & 15;
        int lf = f & 63;
        int row = mt * 16 + (lf & 15);
        int k0  = kt * 32 + (lf >> 4) * 8;
        const float* sp = x + (size_t)(rbase + row) * 512 + k0;
        float4 a = *(const float4*)sp;
        float4 b = *(const float4*)(sp + 4);
        short8 v = cvt8(a, b);
        *(short8*)&sfrag[(size_t)f * 8] = v;
    }

    short8 bw0[16], bw1[16];
    f32x4 acc[2][4];
    #pragma unroll
    for (int mt = 0; mt < 2; ++mt)
        #pragma unroll
        for (int nt = 0; nt < 4; ++nt)
            acc[mt][nt] = (f32x4){0.f, 0.f, 0.f, 0.f};

    LOAD_PANEL(Wx_w, w * 64);
    __syncthreads();    // sfrag visible + vmcnt drained -> clean ring baseline

    {   // prologue: stage Wx chunk 0 -> slot 0 (4 issues in flight)
        gl_lds16f(Wx_w + s00, ringf + ((w * 2 + 0) * 2 + 0) * 512);
        gl_lds16f(Wx_w + s10, ringf + ((w * 2 + 0) * 2 + 0) * 512 + 256);
        gl_lds16f(Wx_w + s01, ringf + ((w * 2 + 0) * 2 + 1) * 512);
        gl_lds16f(Wx_w + s11, ringf + ((w * 2 + 0) * 2 + 1) * 512 + 256);
    }

    // ---- xproj (tail kt=15 stages Wh chunk 0 into slot 0) ----
    ring_gemm<true>(sfrag, ringf, Wh_w, Wx_w, bw0, bw1, acc,
                    w, l, s00, s01, s10, s11, u0off, u1off);

    unsigned xpk[2][4][2];
    #pragma unroll
    for (int mt = 0; mt < 2; ++mt)
        #pragma unroll
        for (int nt = 0; nt < 4; ++nt) {
            float b = bsum[nt];
            xpk[mt][nt][0] = pk2(acc[mt][nt][0] + b, acc[mt][nt][1] + b);
            xpk[mt][nt][1] = pk2(acc[mt][nt][2] + b, acc[mt][nt][3] + b);
            acc[mt][nt] = (f32x4){0.f, 0.f, 0.f, 0.f};
        }
    WAITLG0(); __builtin_amdgcn_s_barrier();   // xproj sfrag reads done; DMA in flight

    // Wh panel (flat loads; implicit waits may drain ring stages — invariant
    // self-heals at step-1 kt=0, data already resident)
    LOAD_PANEL(Wh_w, w * 64);

    // zero hist (tid-private) + state
    uint4 z4 = {0u, 0u, 0u, 0u};
    #pragma unroll
    for (int sb = 0; sb < 8; ++sb) *(uint4*)&histu[(sb * 512 + tid) * 4] = z4;
    float s[2][4][4];
    unsigned h0[2][4][2];
    #pragma unroll
    for (int mt = 0; mt < 2; ++mt)
        #pragma unroll
        for (int nt = 0; nt < 4; ++nt) {
            #pragma unroll
            for (int i = 0; i < 4; ++i) s[mt][nt][i] = 0.f;
            h0[mt][nt][0] = h0[mt][nt][1] = 0u;
        }

    const int tIdx = (w * 2048 + q * 64 + (l & 7) * 2 + (((l >> 3) & 1) << 8)) >> 1;

    // ---- recurrence (SA alternates; nsteps even in practice, tail-safe) ----
    #define DS(A) do_step<A>(s, h0, acc, xpk, sfrag, histu, ringf, Wh_w, bw0, bw1, \
                             w, l, tid, tIdx, s00, s01, s10, s11, u0off, u1off, g1, g2, g3)
    int t = 0;
    while (t + 2 <= nsteps) {
        DS(1); DS(0);
        t += 2;
    }
    if (t < nsteps) { DS(1); ++t; }
    #undef DS

    // ---- head: out = s_final @ Head^T + Head_b (R9-verified direct stream) ----
    scatter_s(s, sfrag, tIdx);
    WAITLG0(); __builtin_amdgcn_s_barrier();
    WAITV(0);   // drain leftover ring stages

    f32x4 acch[2][2];
    #pragma unroll
    for (int mt = 0; mt < 2; ++mt)
        #pragma unroll
        for (int nt = 0; nt < 2; ++nt)
            acch[mt][nt] = (f32x4){0.f, 0.f, 0.f, 0.f};
    gemm_f32B<2, 16>(sfrag, Hd_w, acch, w, l);

    #pragma unroll
    for (int nt = 0; nt < 2; ++nt) {
        int col = w * 32 + nt * 16 + c;
        float hb = nt ? hb1 : hb0;
        #pragma unroll
        for (int mt = 0; mt < 2; ++mt)
            #pragma unroll
            for (int i = 0; i < 4; ++i)
                out[(size_t)(rbase + mt * 16 + q * 4 + i) * 256 + col] = acch[mt][nt][i] + hb;
    }
}

extern "C" void kernel_launch(void* const* d_in, const int* in_sizes, int n_in,
                              void* d_out, int out_size, void* d_ws, size_t ws_size,
                              hipStream_t stream) {
    (void)n_in; (void)out_size; (void)d_ws; (void)ws_size;
    const float* x    = (const float*)d_in[0];
    const float* Wx_w = (const float*)d_in[1];
    const float* Wx_b = (const float*)d_in[2];
    const float* Wh_w = (const float*)d_in[3];
    const float* Wh_b = (const float*)d_in[4];
    const float* Hd_w = (const float*)d_in[5];
    const float* Hd_b = (const float*)d_in[6];
    const float* gma  = (const float*)d_in[7];
    const float* alp  = (const float*)d_in[8];
    const int*   stp  = (const int*)d_in[9];
    float* out = (float*)d_out;

    int batch = in_sizes[0] / 512;                 // 8192
    int nblk  = batch / 32;                        // 256 blocks, 1 per CU
    toroidal<<<nblk, THREADS, 0, stream>>>(x, Wx_w, Wx_b, Wh_w, Wh_b, Hd_w, Hd_b,
                                           gma, alp, stp, out);
}

// Round 16
// 693.209 us; speedup vs baseline: 2.4520x; 1.7334x over previous
//
#include <hip/hip_runtime.h>
#include <hip/hip_bf16.h>

typedef __attribute__((ext_vector_type(8))) short short8;
typedef __attribute__((ext_vector_type(4))) float f32x4;

#define THREADS 512
#define MFMA(a, b, c) __builtin_amdgcn_mfma_f32_16x16x32_bf16((a), (b), (c), 0, 0, 0)
#define WAITV(N) asm volatile("s_waitcnt vmcnt(" #N ")" ::: "memory")
#define WAITLG0() asm volatile("s_waitcnt lgkmcnt(0)" ::: "memory")

static __device__ __forceinline__ unsigned short f2bf(float x) {
    __hip_bfloat16 h = __float2bfloat16(x);
    return __builtin_bit_cast(unsigned short, h);
}
static __device__ __forceinline__ unsigned pk2(float a, float b) {
    return (unsigned)f2bf(a) | ((unsigned)f2bf(b) << 16);
}
static __device__ __forceinline__ float bflo(unsigned u) {
    unsigned v = u << 16; return __builtin_bit_cast(float, v);
}
static __device__ __forceinline__ float bfhi(unsigned u) {
    unsigned v = u & 0xffff0000u; return __builtin_bit_cast(float, v);
}
static __device__ __forceinline__ float fast_tanh(float x) {
    float e = __builtin_amdgcn_exp2f(x * 2.885390081777927f);
    float r = __builtin_amdgcn_rcpf(e + 1.0f);
    return fmaf(-2.0f, r, 1.0f);
}
static __device__ __forceinline__ short8 cvt8(float4 a, float4 b) {
    short8 r;
    r[0] = (short)f2bf(a.x); r[1] = (short)f2bf(a.y);
    r[2] = (short)f2bf(a.z); r[3] = (short)f2bf(a.w);
    r[4] = (short)f2bf(b.x); r[5] = (short)f2bf(b.y);
    r[6] = (short)f2bf(b.z); r[7] = (short)f2bf(b.w);
    return r;
}
static __device__ __forceinline__ void gl_lds16(const unsigned short* g, unsigned short* l) {
    __builtin_amdgcn_global_load_lds(
        (const __attribute__((address_space(1))) unsigned int*)g,
        (__attribute__((address_space(3))) unsigned int*)l, 16, 0, 0);   // aux=0: L2-cacheable
}

// Repack row-major [N][512] f32 -> bf16 fragment chunks, layout [kt][ntg][lane][8e]
// (R2/R10-verified): frag f=(kt*NTG+ntg)*64+lane holds M[ntg*16+(lane&15)][kt*32+(lane>>4)*8+e]
__global__ __launch_bounds__(256) void pack_weights(
    const float* __restrict__ wh, const float* __restrict__ wx,
    const float* __restrict__ hd,
    unsigned short* __restrict__ whp, unsigned short* __restrict__ wxp,
    unsigned short* __restrict__ hdp)
{
    int gid = blockIdx.x * 256 + threadIdx.x;          // [0, 81920)
    const float* src; unsigned short* dst; int f, lane, kt, ntg;
    if (gid < 32768)      { f = gid;         lane = f & 63; ntg = (f >> 6) & 31; kt = f >> 11; src = wh; dst = whp; }
    else if (gid < 65536) { f = gid - 32768; lane = f & 63; ntg = (f >> 6) & 31; kt = f >> 11; src = wx; dst = wxp; }
    else                  { f = gid - 65536; lane = f & 63; ntg = (f >> 6) & 15; kt = f >> 10; src = hd; dst = hdp; }
    int n = ntg * 16 + (lane & 15);
    int k = kt * 32 + (lane >> 4) * 8;
    const float* sp = src + (size_t)n * 512 + k;
    float4 a = *(const float4*)sp;
    float4 b = *(const float4*)(sp + 4);
    uint4 o;
    o.x = pk2(a.x, a.y); o.y = pk2(a.z, a.w);
    o.z = pk2(b.x, b.y); o.w = pk2(b.z, b.w);
    *(uint4*)(dst + (size_t)f * 8) = o;
}

// Ring GEMM over 32 subs (sub = (kt, nt-pair p): 2 frags = 2 KB = 2 gl_lds of
// 1 KB, both sides linear). Per-wave-private 3-slot x 2 KB ring, no barriers
// inside. Invariant: 4 issues (subs c, c+1) in flight at sub-c entry; stage
// c+2 (2 issues) -> 6 -> WAITV(4) = sub c resident. Self-heals after drains.
// Staging source selector uses the STAGED sub: during xproj, c<30 stages wxp
// (cn=2..31) and c=30,31 stage next pass's whp subs 0,1 (cn wraps).
template<int PHASE, bool XPROJ>
static __device__ __forceinline__ void ring_gemm(
    const unsigned short* sfr, unsigned short* ring,
    const unsigned short* __restrict__ whp, const unsigned short* __restrict__ wxp,
    f32x4 (&acc)[2][4], const int w, const int l)
{
    #pragma unroll
    for (int c = 0; c < 32; ++c) {
        const int kt = c >> 1, p = c & 1;
        const int slot  = (PHASE + c) % 3;
        const int cn    = (c + 2) & 31;
        const int ktn   = cn >> 1, pn = cn & 1;
        const int slotn = (PHASE + c + 2) % 3;
        const unsigned short* gsrc = (XPROJ && c < 30) ? wxp : whp;
        WAITLG0();   // prior ds_reads of slotn (sub c-1) complete before DMA overwrite
        {
            const unsigned short* src = gsrc + (size_t)(ktn * 32 + w * 4 + 2 * pn) * 512 + l * 8;
            unsigned short* dst = ring + (w * 3 + slotn) * 1024;
            gl_lds16(src,       dst);
            gl_lds16(src + 512, dst + 512);
        }
        WAITV(4);
        short8 a0 = *(const short8*)(sfr + (kt * 64 + l) * 8);
        short8 a1 = *(const short8*)(sfr + ((16 + kt) * 64 + l) * 8);
        short8 b0 = *(const short8*)(ring + (w * 3 + slot) * 1024 + l * 8);
        short8 b1 = *(const short8*)(ring + (w * 3 + slot) * 1024 + 512 + l * 8);
        const int nt0 = 2 * p, nt1 = 2 * p + 1;
        acc[0][nt0] = MFMA(a0, b0, acc[0][nt0]);
        acc[1][nt0] = MFMA(a1, b0, acc[1][nt0]);
        acc[0][nt1] = MFMA(a0, b1, acc[0][nt1]);
        acc[1][nt1] = MFMA(a1, b1, acc[1][nt1]);
    }
}

// Direct-load f32-B GEMM (R9/R12-verified) — head only.
template<int NT, int NKT_S>
static __device__ __forceinline__ void gemm_f32B(
    const unsigned short* sfr, const float* __restrict__ Wsrc,
    f32x4 (&acc)[2][NT], const int w, const int l)
{
    const int q = l >> 4, c = l & 15;
    const float* bp = Wsrc + (size_t)(w * (NT * 16) + c) * 512 + q * 8;
    float4 fa[NT][2], fb[NT][2];
    #pragma unroll
    for (int nt = 0; nt < NT; ++nt) {
        fa[nt][0] = *(const float4*)(bp + nt * 8192);
        fa[nt][1] = *(const float4*)(bp + nt * 8192 + 4);
    }
    #pragma unroll
    for (int kt = 0; kt < NKT_S; ++kt) {
        if (kt + 1 < NKT_S) {
            #pragma unroll
            for (int nt = 0; nt < NT; ++nt) {
                fb[nt][0] = *(const float4*)(bp + nt * 8192 + (kt + 1) * 32);
                fb[nt][1] = *(const float4*)(bp + nt * 8192 + (kt + 1) * 32 + 4);
            }
        }
        short8 a0 = *(const short8*)(sfr + (kt * 64 + l) * 8);
        short8 a1 = *(const short8*)(sfr + ((16 + kt) * 64 + l) * 8);
        #pragma unroll
        for (int nt = 0; nt < NT; ++nt) {
            short8 b = cvt8(fa[nt][0], fa[nt][1]);
            acc[0][nt] = MFMA(a0, b, acc[0][nt]);
            acc[1][nt] = MFMA(a1, b, acc[1][nt]);
        }
        if (kt + 1 < NKT_S) {
            #pragma unroll
            for (int nt = 0; nt < NT; ++nt) { fa[nt][0] = fb[nt][0]; fa[nt][1] = fb[nt][1]; }
        }
    }
}

static __device__ __forceinline__ void scatter_s(const float (&s)[2][4][4],
    unsigned short* sfrag, const int tIdx)
{
    #pragma unroll
    for (int mt = 0; mt < 2; ++mt)
        #pragma unroll
        for (int nt = 0; nt < 4; ++nt)
            #pragma unroll
            for (int i = 0; i < 4; ++i) {
                const int off = (mt * 16384 + (nt >> 1) * 1024 + ((2 * nt) & 3) * 256 + i * 16) >> 1;
                sfrag[tIdx + off] = f2bf(s[mt][nt][i]);
            }
}

// One step. SA = t&1. R12-verified lag structure: h0 = s_{t-2} (regs),
// histu[SA] = s_{t-3}, histu[SA^1] = s_{t-4} (tid-private LDS).
template<int PHASE, int SA>
static __device__ __forceinline__ void do_step(
    float (&s)[2][4][4], unsigned (&h0)[2][4][2], f32x4 (&acc)[2][4],
    const unsigned (&xpk)[2][4][2],
    unsigned short* sfrag, unsigned* histu, unsigned short* ring,
    const unsigned short* __restrict__ whp,
    const int w, const int l, const int tid, const int tIdx,
    const float g1, const float g2, const float g3)
{
    scatter_s(s, sfrag, tIdx);
    WAITLG0(); __builtin_amdgcn_s_barrier();   // raw barrier: ring DMA stays in flight

    ring_gemm<PHASE, false>(sfrag, ring, whp, nullptr, acc, w, l);
    WAITLG0(); __builtin_amdgcn_s_barrier();   // all sfrag reads done before next scatter

    const int sB = SA ^ 1;
    #pragma unroll
    for (int mt = 0; mt < 2; ++mt)
        #pragma unroll
        for (int g = 0; g < 2; ++g) {
            uint4 hA = *(uint4*)&histu[((SA * 2 + mt) * 512 + tid) * 8 + g * 4];
            uint4 hB = *(uint4*)&histu[((sB * 2 + mt) * 512 + tid) * 8 + g * 4];
            uint4 nB;
            #pragma unroll
            for (int ntl = 0; ntl < 2; ++ntl) {
                const int nt = g * 2 + ntl;
                #pragma unroll
                for (int p = 0; p < 2; ++p) {
                    unsigned u1 = h0[mt][nt][p];
                    unsigned u2 = ((unsigned*)&hA)[ntl * 2 + p];
                    unsigned u3 = ((unsigned*)&hB)[ntl * 2 + p];
                    unsigned ux = xpk[mt][nt][p];
                    float pre0 = acc[mt][nt][2 * p] + bflo(ux)
                               + g1 * bflo(u1) + g2 * bflo(u2) + g3 * bflo(u3);
                    float pre1 = acc[mt][nt][2 * p + 1] + bfhi(ux)
                               + g1 * bfhi(u1) + g2 * bfhi(u2) + g3 * bfhi(u3);
                    float so0 = s[mt][nt][2 * p], so1 = s[mt][nt][2 * p + 1];
                    s[mt][nt][2 * p]     = 0.5f * so0 + 0.5f * fast_tanh(pre0);
                    s[mt][nt][2 * p + 1] = 0.5f * so1 + 0.5f * fast_tanh(pre1);
                    ((unsigned*)&nB)[ntl * 2 + p] = u1;     // s_{t-2} -> becomes s_{t'-4}
                    h0[mt][nt][p] = pk2(so0, so1);          // s_{t-1} for next step
                }
            }
            *(uint4*)&histu[((sB * 2 + mt) * 512 + tid) * 8 + g * 4] = nB;
            acc[mt][g * 2 + 0] = (f32x4){0.f, 0.f, 0.f, 0.f};
            acc[mt][g * 2 + 1] = (f32x4){0.f, 0.f, 0.f, 0.f};
        }
}

__global__ __attribute__((amdgpu_flat_work_group_size(512, 512), amdgpu_waves_per_eu(2, 2)))
void toroidal(
    const float* __restrict__ x,
    const unsigned short* __restrict__ wxp,
    const unsigned short* __restrict__ whp,
    const float* __restrict__ wxb, const float* __restrict__ whb,
    const float* __restrict__ Hd_w, const float* __restrict__ hdb,
    const float* __restrict__ gamma_p, const float* __restrict__ alphas,
    const int* __restrict__ steps_p,
    float* __restrict__ out)
{
    __shared__ __align__(16) unsigned short sfrag[16384];     // 32 KB A-frags [mt2][kt16][lane64][e8]
    __shared__ __align__(16) unsigned short ring[24576];      // 48 KB ring [wave8][slot3][1024 sh]
    __shared__ __align__(16) unsigned histu[2 * 2 * 512 * 8]; // 64 KB hist [slot2][mt2][tid][8 u32]

    const int tid = threadIdx.x;
    const int w = tid >> 6;
    const int l = tid & 63;
    const int q = l >> 4;
    const int c = l & 15;
    const int rbase = blockIdx.x * 32;

    const float gm = gamma_p[0];
    const float g1 = gm * alphas[0], g2 = gm * alphas[1], g3 = gm * alphas[2];
    const int nsteps = steps_p[0];

    float bsum[4];
    #pragma unroll
    for (int nt = 0; nt < 4; ++nt) {
        int col = w * 64 + nt * 16 + c;
        bsum[nt] = wxb[col] + whb[col];
    }
    const float hb0 = hdb[w * 32 + c], hb1 = hdb[w * 32 + 16 + c];

    // ---- pack x tile (32 rows) into sfrag as bf16 A-frags (verified) ----
    #pragma unroll
    for (int j = 0; j < 4; ++j) {
        int f = tid + j * THREADS;
        int mt = f >> 10;
        int kt = (f >> 6) & 15;
        int lf = f & 63;
        int row = mt * 16 + (lf & 15);
        int k0  = kt * 32 + (lf >> 4) * 8;
        const float* sp = x + (size_t)(rbase + row) * 512 + k0;
        float4 a = *(const float4*)sp;
        float4 b = *(const float4*)(sp + 4);
        short8 v = cvt8(a, b);
        *(short8*)&sfrag[(size_t)f * 8] = v;
    }
    __syncthreads();    // sfrag visible + vmcnt drained -> clean ring baseline

    f32x4 acc[2][4];
    #pragma unroll
    for (int mt = 0; mt < 2; ++mt)
        #pragma unroll
        for (int nt = 0; nt < 4; ++nt)
            acc[mt][nt] = (f32x4){0.f, 0.f, 0.f, 0.f};

    {   // prologue: stage wxp subs 0,1 into slots 0,1 (4 issues in flight)
        #pragma unroll
        for (int cs = 0; cs < 2; ++cs) {
            const unsigned short* src = wxp + (size_t)((cs >> 1) * 32 + w * 4 + 2 * (cs & 1)) * 512 + l * 8;
            unsigned short* dst = ring + (w * 3 + cs) * 1024;
            gl_lds16(src,       dst);
            gl_lds16(src + 512, dst + 512);
        }
    }

    // ---- xproj (PHASE=0; subs 30,31 stage whp subs 0,1 for step 1) ----
    ring_gemm<0, true>(sfrag, ring, whp, wxp, acc, w, l);

    unsigned xpk[2][4][2];
    #pragma unroll
    for (int mt = 0; mt < 2; ++mt)
        #pragma unroll
        for (int nt = 0; nt < 4; ++nt) {
            float b = bsum[nt];
            xpk[mt][nt][0] = pk2(acc[mt][nt][0] + b, acc[mt][nt][1] + b);
            xpk[mt][nt][1] = pk2(acc[mt][nt][2] + b, acc[mt][nt][3] + b);
            acc[mt][nt] = (f32x4){0.f, 0.f, 0.f, 0.f};
        }
    WAITLG0(); __builtin_amdgcn_s_barrier();   // xproj sfrag reads done; DMA in flight

    // zero hist (tid-private) + state
    uint4 z4 = {0u, 0u, 0u, 0u};
    #pragma unroll
    for (int sb = 0; sb < 8; ++sb) *(uint4*)&histu[(sb * 512 + tid) * 4] = z4;
    float s[2][4][4];
    unsigned h0[2][4][2];
    #pragma unroll
    for (int mt = 0; mt < 2; ++mt)
        #pragma unroll
        for (int nt = 0; nt < 4; ++nt) {
            #pragma unroll
            for (int i = 0; i < 4; ++i) s[mt][nt][i] = 0.f;
            h0[mt][nt][0] = h0[mt][nt][1] = 0u;
        }

    const int tIdx = (w * 2048 + q * 64 + (l & 7) * 2 + (((l >> 3) & 1) << 8)) >> 1;

    // ---- recurrence: pass k has PHASE=(2k)%3; xproj was pass 0, so steps
    // cycle PHASE 2,1,0. SA alternates 1,0. Joint period 6; nsteps=30 fits. ----
    #define DS(P, A) do_step<P, A>(s, h0, acc, xpk, sfrag, histu, ring, whp, \
                                   w, l, tid, tIdx, g1, g2, g3)
    int t = 0;
    while (t + 6 <= nsteps) {
        DS(2, 1); DS(1, 0); DS(0, 1); DS(2, 0); DS(1, 1); DS(0, 0);
        t += 6;
    }
    if (t < nsteps) { DS(2, 1); ++t; }
    if (t < nsteps) { DS(1, 0); ++t; }
    if (t < nsteps) { DS(0, 1); ++t; }
    if (t < nsteps) { DS(2, 0); ++t; }
    if (t < nsteps) { DS(1, 1); ++t; }
    #undef DS

    // ---- head: out = s_final @ Head^T + Head_b (R9/R12-verified) ----
    scatter_s(s, sfrag, tIdx);
    WAITLG0(); __builtin_amdgcn_s_barrier();
    WAITV(0);   // drain leftover ring stages

    f32x4 acch[2][2];
    #pragma unroll
    for (int mt = 0; mt < 2; ++mt)
        #pragma unroll
        for (int nt = 0; nt < 2; ++nt)
            acch[mt][nt] = (f32x4){0.f, 0.f, 0.f, 0.f};
    gemm_f32B<2, 16>(sfrag, Hd_w, acch, w, l);

    #pragma unroll
    for (int nt = 0; nt < 2; ++nt) {
        int col = w * 32 + nt * 16 + c;
        float hb = nt ? hb1 : hb0;
        #pragma unroll
        for (int mt = 0; mt < 2; ++mt)
            #pragma unroll
            for (int i = 0; i < 4; ++i)
                out[(size_t)(rbase + mt * 16 + q * 4 + i) * 256 + col] = acch[mt][nt][i] + hb;
    }
}

extern "C" void kernel_launch(void* const* d_in, const int* in_sizes, int n_in,
                              void* d_out, int out_size, void* d_ws, size_t ws_size,
                              hipStream_t stream) {
    (void)n_in; (void)out_size;
    const float* x    = (const float*)d_in[0];
    const float* Wx_w = (const float*)d_in[1];
    const float* Wx_b = (const float*)d_in[2];
    const float* Wh_w = (const float*)d_in[3];
    const float* Wh_b = (const float*)d_in[4];
    const float* Hd_w = (const float*)d_in[5];
    const float* Hd_b = (const float*)d_in[6];
    const float* gma  = (const float*)d_in[7];
    const float* alp  = (const float*)d_in[8];
    const int*   stp  = (const int*)d_in[9];
    float* out = (float*)d_out;

    // ws: bf16 fragment-packed weights (512KB wh + 512KB wx + 256KB hd)
    if (ws_size < (size_t)(512 * 512 * 2 * 2 + 256 * 512 * 2)) return;
    unsigned short* whp = (unsigned short*)d_ws;
    unsigned short* wxp = whp + 512 * 512;
    unsigned short* hdp = wxp + 512 * 512;

    pack_weights<<<320, 256, 0, stream>>>(Wh_w, Wx_w, Hd_w, whp, wxp, hdp);

    int batch = in_sizes[0] / 512;                 // 8192
    int nblk  = batch / 32;                        // 256 blocks, 1 per CU
    toroidal<<<nblk, THREADS, 0, stream>>>(x, wxp, whp, Wx_b, Wh_b, Hd_w, Hd_b,
                                           gma, alp, stp, out);
}